// Round 1
// baseline (920.727 us; speedup 1.0000x reference)
//
#include <hip/hip_runtime.h>
#include <hip/hip_bf16.h>

// SOMPCell: Y = tanh(0.5*(x1@W1 + x2@W2) + c + 0.1*noise),
//   c[o] = 0.5*(b1+b2) + b + 0.9*bucket - 0.1*|prev|
// Strategy: bf16 MFMA GEMM (m97 128^2-tile structure, global_load_lds w=16,
// XOR-swizzled LDS), fused elementwise epilogue.

typedef __attribute__((ext_vector_type(8))) short short8;
typedef __attribute__((ext_vector_type(4))) float f32x4;

__device__ inline unsigned short bf16_rne(float f) {
    unsigned u = __float_as_uint(f);
    unsigned r = u + 0x7fffu + ((u >> 16) & 1u);
    return (unsigned short)(r >> 16);
}

__device__ inline float fast_tanh(float x) {
    x = fminf(fmaxf(x, -15.f), 15.f);
    float e = __expf(2.0f * x);
    return (e - 1.0f) / (e + 1.0f);
}

// ---------------- conversion kernels ----------------

__global__ void f32_to_bf16_kernel(const float* __restrict__ src,
                                   ushort* __restrict__ dst, int n4) {
    for (int i = blockIdx.x * blockDim.x + threadIdx.x; i < n4;
         i += gridDim.x * blockDim.x) {
        float4 v = ((const float4*)src)[i];
        ushort4 o = make_ushort4(bf16_rne(v.x), bf16_rne(v.y),
                                 bf16_rne(v.z), bf16_rne(v.w));
        ((ushort4*)dst)[i] = o;
    }
}

// W: [K][O] f32 row-major  ->  Wt: [O][K] bf16 row-major
__global__ void transpose_convert_kernel(const float* __restrict__ W,
                                         ushort* __restrict__ Wt,
                                         int K, int O) {
    __shared__ float tile[32][33];
    int bk = blockIdx.x * 32;
    int bo = blockIdx.y * 32;
    int t = threadIdx.x;          // 256 threads
    int r = t >> 3;               // 0..31
    int c4 = (t & 7) * 4;         // 0..28
    float4 v = *(const float4*)(W + (size_t)(bk + r) * O + bo + c4);
    tile[r][c4 + 0] = v.x; tile[r][c4 + 1] = v.y;
    tile[r][c4 + 2] = v.z; tile[r][c4 + 3] = v.w;
    __syncthreads();
    ushort4 w = make_ushort4(bf16_rne(tile[c4 + 0][r]), bf16_rne(tile[c4 + 1][r]),
                             bf16_rne(tile[c4 + 2][r]), bf16_rne(tile[c4 + 3][r]));
    *(ushort4*)(Wt + (size_t)(bo + r) * K + bk + c4) = w;
}

__global__ void make_cvec_kernel(const float* __restrict__ b1, const float* __restrict__ b2,
                                 const float* __restrict__ b,  const float* __restrict__ bucket,
                                 const float* __restrict__ prev, float* __restrict__ c, int n) {
    int i = blockIdx.x * blockDim.x + threadIdx.x;
    if (i < n)
        c[i] = 0.5f * (b1[i] + b2[i]) + b[i] + 0.9f * bucket[i] - 0.1f * fabsf(prev[i]);
}

// ---------------- fused GEMM ----------------
// C[8192][4096] = x1b[8192][4096] @ wt1[4096][4096]^T + x2b[8192][2048] @ wt2[4096][2048]^T
// 128x128 tile, BK=64, 256 threads (4 waves, 2x2), each wave 64x64 (4x4 frags 16x16).

__global__ __launch_bounds__(256) void gemm_fused(
    const ushort* __restrict__ x1b, const ushort* __restrict__ x2b,
    const ushort* __restrict__ wt1, const ushort* __restrict__ wt2,
    const float* __restrict__ cvec, const float* __restrict__ noise,
    float* __restrict__ out) {
    __shared__ __align__(16) char smem[32768];
    char* smA = smem;            // [128 rows][64 k] bf16, 128B/row, XOR-swizzled
    char* smB = smem + 16384;    // [128 o]   [64 k] bf16

    const int tid  = threadIdx.x;
    const int wid  = tid >> 6;
    const int lane = tid & 63;
    const int qw   = lane >> 4;   // 0..3
    const int l15  = lane & 15;
    const int wrow = wid >> 1;    // 0..1
    const int wcol = wid & 1;     // 0..1

    const int m0 = blockIdx.x * 128;
    const int n0 = blockIdx.y * 128;

    f32x4 acc[4][4];
    #pragma unroll
    for (int i = 0; i < 4; ++i)
        #pragma unroll
        for (int j = 0; j < 4; ++j)
            #pragma unroll
            for (int r = 0; r < 4; ++r) acc[i][j][r] = 0.f;

    // linear LDS dest (wave-uniform base); inverse-swizzled global source
    auto stage = [&](const ushort* __restrict__ g, int ld, int row0, int k0, char* base) {
        #pragma unroll
        for (int i = 0; i < 4; ++i) {
            int p   = (i * 256 + tid) << 4;              // phys byte in 16KB tile
            int row = p >> 7;                            // 128B per row
            int lw  = (p & 127) ^ ((row & 7) << 4);      // logical within-row byte
            const ushort* src = g + (size_t)(row0 + row) * ld + k0 + (lw >> 1);
            __builtin_amdgcn_global_load_lds(
                (const __attribute__((address_space(1))) void*)src,
                (__attribute__((address_space(3))) void*)(base + i * 4096 + wid * 1024),
                16, 0, 0);
        }
    };

    auto kstep = [&](const ushort* __restrict__ A, int lda,
                     const ushort* __restrict__ Bt, int ldb, int k0) {
        stage(A, lda, m0, k0, smA);
        stage(Bt, ldb, n0, k0, smB);
        __syncthreads();
        #pragma unroll
        for (int kk = 0; kk < 64; kk += 32) {
            short8 af[4], bfr[4];
            const int kb = (kk + qw * 8) * 2;            // byte offset of 8 bf16 along k
            #pragma unroll
            for (int f = 0; f < 4; ++f) {
                int ra = wrow * 64 + f * 16 + l15;
                af[f] = *(const short8*)(smA + ra * 128 + (kb ^ ((ra & 7) << 4)));
                int rb = wcol * 64 + f * 16 + l15;
                bfr[f] = *(const short8*)(smB + rb * 128 + (kb ^ ((rb & 7) << 4)));
            }
            #pragma unroll
            for (int mf = 0; mf < 4; ++mf)
                #pragma unroll
                for (int nf = 0; nf < 4; ++nf)
                    acc[mf][nf] = __builtin_amdgcn_mfma_f32_16x16x32_bf16(
                        af[mf], bfr[nf], acc[mf][nf], 0, 0, 0);
        }
        __syncthreads();
    };

    for (int k0 = 0; k0 < 4096; k0 += 64) kstep(x1b, 4096, wt1, 4096, k0);
    for (int k0 = 0; k0 < 2048; k0 += 64) kstep(x2b, 2048, wt2, 2048, k0);

    // epilogue: Y = tanh(0.5*acc + c[o] + 0.1*noise)
    #pragma unroll
    for (int mf = 0; mf < 4; ++mf) {
        #pragma unroll
        for (int r = 0; r < 4; ++r) {
            int m = m0 + wrow * 64 + mf * 16 + qw * 4 + r;
            const float* nrow = noise + (size_t)m * 4096;
            float* orow = out + (size_t)m * 4096;
            #pragma unroll
            for (int nf = 0; nf < 4; ++nf) {
                int o = n0 + wcol * 64 + nf * 16 + l15;
                float v = 0.5f * acc[mf][nf][r] + cvec[o] + 0.1f * nrow[o];
                orow[o] = fast_tanh(v);
            }
        }
    }
}

// ---------------- launch ----------------

extern "C" void kernel_launch(void* const* d_in, const int* in_sizes, int n_in,
                              void* d_out, int out_size, void* d_ws, size_t ws_size,
                              hipStream_t stream) {
    const float* x1     = (const float*)d_in[0];   // (4,2048,4096)
    const float* x2     = (const float*)d_in[1];   // (4,2048,2048)
    const float* noise  = (const float*)d_in[2];   // (4,2048,4096)
    const float* W1     = (const float*)d_in[3];   // (4096,4096)
    const float* b1     = (const float*)d_in[4];
    const float* W2     = (const float*)d_in[5];   // (2048,4096)
    const float* b2     = (const float*)d_in[6];
    const float* b      = (const float*)d_in[7];
    const float* bucket = (const float*)d_in[8];
    const float* prev   = (const float*)d_in[9];
    float* out = (float*)d_out;

    char* ws = (char*)d_ws;
    ushort* x1b = (ushort*)ws;                               // 64 MiB
    ushort* x2b = (ushort*)(ws + (size_t)67108864);          // 32 MiB
    ushort* wt1 = (ushort*)(ws + (size_t)100663296);         // 32 MiB
    ushort* wt2 = (ushort*)(ws + (size_t)134217728);         // 16 MiB
    float*  cv  = (float*) (ws + (size_t)150994944);         // 16 KiB

    f32_to_bf16_kernel<<<2048, 256, 0, stream>>>(x1, x1b, (8192 * 4096) / 4);
    f32_to_bf16_kernel<<<2048, 256, 0, stream>>>(x2, x2b, (8192 * 2048) / 4);
    transpose_convert_kernel<<<dim3(128, 128), 256, 0, stream>>>(W1, wt1, 4096, 4096);
    transpose_convert_kernel<<<dim3(64, 128), 256, 0, stream>>>(W2, wt2, 2048, 4096);
    make_cvec_kernel<<<16, 256, 0, stream>>>(b1, b2, b, bucket, prev, cv, 4096);
    gemm_fused<<<dim3(64, 32), 256, 0, stream>>>(x1b, x2b, wt1, wt2, cv, noise, out);
}